// Round 7
// baseline (643.440 us; speedup 1.0000x reference)
//
#include <hip/hip_runtime.h>

#define FDIM 128
#define NCLS 16

#define SCAN_T 256
#define SCAN_I 8
#define SCAN_CHUNK (SCAN_T * SCAN_I)  // 2048 elements per block

// ---------------- CSR build ----------------
__global__ void k_zero_cnt(int* cnt, int n) {
    int i = blockIdx.x * blockDim.x + threadIdx.x;
    if (i < n) cnt[i] = 0;
}

__global__ void k_count(const int* __restrict__ dst, int* cnt, int e) {
    int i = blockIdx.x * blockDim.x + threadIdx.x;
    if (i < e) atomicAdd(&cnt[dst[i]], 1);
}

// phase 1: block-local exclusive scan, per-block total; also computes dinv
__global__ __launch_bounds__(SCAN_T) void k_scan1(const int* __restrict__ cnt,
                                                  int* __restrict__ excl,
                                                  int* __restrict__ blockSum,
                                                  float* __restrict__ dinv, int n) {
    __shared__ int ts[SCAN_T];
    int b = blockIdx.x, t = threadIdx.x;
    int base = b * SCAN_CHUNK + t * SCAN_I;
    int v[SCAN_I];
    int s = 0;
    #pragma unroll
    for (int i = 0; i < SCAN_I; ++i) {
        int idx = base + i;
        v[i] = (idx < n) ? cnt[idx] : 0;
        if (idx < n) dinv[idx] = rsqrtf((float)(v[i] + 1));  // +1 self-loop
        s += v[i];
    }
    ts[t] = s;
    __syncthreads();
    for (int off = 1; off < SCAN_T; off <<= 1) {
        int x = (t >= off) ? ts[t - off] : 0;
        __syncthreads();
        ts[t] += x;
        __syncthreads();
    }
    int ex = (t == 0) ? 0 : ts[t - 1];
    #pragma unroll
    for (int i = 0; i < SCAN_I; ++i) {
        int idx = base + i;
        if (idx < n) excl[idx] = ex;
        ex += v[i];
    }
    if (t == SCAN_T - 1) blockSum[b] = ts[SCAN_T - 1];
}

// phase 2: single block exclusive-scans the block totals (nb <= 1024)
__global__ __launch_bounds__(1024) void k_scan2(int* blockSum, int* total, int nb) {
    __shared__ int ts[1024];
    int t = threadIdx.x;
    int v = (t < nb) ? blockSum[t] : 0;
    ts[t] = v;
    __syncthreads();
    for (int off = 1; off < 1024; off <<= 1) {
        int x = (t >= off) ? ts[t - off] : 0;
        __syncthreads();
        ts[t] += x;
        __syncthreads();
    }
    if (t < nb) blockSum[t] = (t == 0) ? 0 : ts[t - 1];
    if (t == 1023) *total = ts[1023];
}

// phase 3: add block offsets, copy to cursor, write row_ptr[n]
__global__ void k_scan3(int* __restrict__ row_ptr, int* __restrict__ cursor,
                        const int* __restrict__ blockSum, const int* __restrict__ total,
                        int n) {
    int i = blockIdx.x * blockDim.x + threadIdx.x;
    if (i < n) {
        int v = row_ptr[i] + blockSum[i / SCAN_CHUNK];
        row_ptr[i] = v;
        cursor[i] = v;
    }
    if (i == 0) row_ptr[n] = *total;
}

// scatter: store BYTE offset of source row (src * 512) for addr-free gathers
__global__ void k_scatter(const int* __restrict__ src, const int* __restrict__ dst,
                          int* cursor, int* __restrict__ csr_off, int e) {
    int i = blockIdx.x * blockDim.x + threadIdx.x;
    if (i >= e) return;
    int pos = atomicAdd(&cursor[dst[i]], 1);
    csr_off[pos] = src[i] << 9;  // fp32 row stride = 128*4 = 512 B
}

// ---------------- GEMM: Y[n,128] = (A[n,128] @ W[128,128]) * dinv[row] ----------------
// 512 threads, 128x128 tile, 8 rows x 4 cols per thread
#define GT 512
#define GR 128
__global__ __launch_bounds__(GT) void k_gemm128(const float* __restrict__ A,
                                                const float* __restrict__ W,
                                                const float* __restrict__ dinv,
                                                float* __restrict__ C, int n) {
    __shared__ float ws[128 * 128];   // [k][c], 64 KB
    __shared__ float xs[GR * 132];    // [r][k] padded to 132
    int t = threadIdx.x;
    const float4* W4 = reinterpret_cast<const float4*>(W);
    #pragma unroll
    for (int i = t; i < 128 * 32; i += GT)
        reinterpret_cast<float4*>(ws)[i] = W4[i];

    int row0 = blockIdx.x * GR;
    for (int i = t; i < GR * 32; i += GT) {
        int r = i >> 5, k4 = i & 31;
        float4 v = (row0 + r < n)
                       ? reinterpret_cast<const float4*>(A)[(size_t)(row0 + r) * 32 + k4]
                       : make_float4(0.f, 0.f, 0.f, 0.f);
        *reinterpret_cast<float4*>(&xs[r * 132 + k4 * 4]) = v;
    }
    __syncthreads();

    int tc = t & 31, tr = t >> 5;   // tr 0..15
    int c0 = tc * 4, r0 = tr * 8;
    float4 acc[8] = {};
    for (int k = 0; k < 128; k += 4) {
        float4 a[8];
        #pragma unroll
        for (int i = 0; i < 8; ++i)
            a[i] = *reinterpret_cast<const float4*>(&xs[(r0 + i) * 132 + k]);
        #pragma unroll
        for (int kk = 0; kk < 4; ++kk) {
            float4 w4 = *reinterpret_cast<const float4*>(&ws[(k + kk) * 128 + c0]);
            #pragma unroll
            for (int i = 0; i < 8; ++i) {
                float av = (kk == 0) ? a[i].x : (kk == 1) ? a[i].y : (kk == 2) ? a[i].z : a[i].w;
                acc[i].x += av * w4.x;
                acc[i].y += av * w4.y;
                acc[i].z += av * w4.z;
                acc[i].w += av * w4.w;
            }
        }
    }
    #pragma unroll
    for (int i = 0; i < 8; ++i) {
        int r = row0 + r0 + i;
        if (r < n) {
            float s = dinv[r];
            reinterpret_cast<float4*>(C)[(size_t)r * 32 + tc] =
                make_float4(acc[i].x * s, acc[i].y * s, acc[i].z * s, acc[i].w * s);
        }
    }
}

// ---------------- aggregation (+ optional fused classifier/softmax) ----------------
// One wave per node. Row = 32 float4. Lanes 0-31 handle even edges, lanes 32-63
// odd edges (2 edges per dwordx4 load). Indices: one coalesced load per 64 edges
// + ds_bpermute broadcast; csr_off holds byte offsets (src*512).
template <bool FUSE>
__global__ __launch_bounds__(256) void k_agg(const float* __restrict__ Y,
                                             const int* __restrict__ csr_off,
                                             const int* __restrict__ row_ptr,
                                             const float* __restrict__ dinv,
                                             const float* __restrict__ bias,
                                             const float* __restrict__ Wl,
                                             const float* __restrict__ bl,
                                             float* __restrict__ out, int n) {
    __shared__ float s_wl[NCLS * FDIM];  // transposed: [c][k]
    __shared__ float s_bl[NCLS];
    if (FUSE) {
        for (int i = threadIdx.x; i < FDIM * NCLS / 4; i += 256) {
            int k = i >> 2, c4 = (i & 3) * 4;
            float4 v = reinterpret_cast<const float4*>(Wl)[i];
            s_wl[(c4 + 0) * FDIM + k] = v.x;
            s_wl[(c4 + 1) * FDIM + k] = v.y;
            s_wl[(c4 + 2) * FDIM + k] = v.z;
            s_wl[(c4 + 3) * FDIM + k] = v.w;
        }
        if (threadIdx.x < NCLS) s_bl[threadIdx.x] = bl[threadIdx.x];
        __syncthreads();
    }

    int node = blockIdx.x * 4 + (threadIdx.x >> 6);
    if (node >= n) return;
    int lane = threadIdx.x & 63;
    int half = lane >> 5, l32 = lane & 31;
    int lo = l32 * 16;  // byte offset of this lane's float4 within a row

    const char* Yb = reinterpret_cast<const char*>(Y);
    // self row: all 64 lanes load (halves redundant; hides latency, 1 instr)
    float4 selfv = *reinterpret_cast<const float4*>(Yb + ((size_t)node << 9) + lo);

    int beg = row_ptr[node], end = row_ptr[node + 1];
    float4 acc = make_float4(0.f, 0.f, 0.f, 0.f);

    for (int j0 = beg; j0 < end; j0 += 64) {
        int cnt = min(64, end - j0);
        int myoff = (j0 + lane < end) ? csr_off[j0 + lane] : 0;
        int k = 0;
        for (; k + 8 <= cnt; k += 8) {
            int o0 = __shfl(myoff, k + 0 + half, 64);
            int o1 = __shfl(myoff, k + 2 + half, 64);
            int o2 = __shfl(myoff, k + 4 + half, 64);
            int o3 = __shfl(myoff, k + 6 + half, 64);
            float4 v0 = *reinterpret_cast<const float4*>(Yb + o0 + lo);
            float4 v1 = *reinterpret_cast<const float4*>(Yb + o1 + lo);
            float4 v2 = *reinterpret_cast<const float4*>(Yb + o2 + lo);
            float4 v3 = *reinterpret_cast<const float4*>(Yb + o3 + lo);
            acc.x += (v0.x + v1.x) + (v2.x + v3.x);
            acc.y += (v0.y + v1.y) + (v2.y + v3.y);
            acc.z += (v0.z + v1.z) + (v2.z + v3.z);
            acc.w += (v0.w + v1.w) + (v2.w + v3.w);
        }
        for (; k + 2 <= cnt; k += 2) {
            int o = __shfl(myoff, k + half, 64);
            float4 v = *reinterpret_cast<const float4*>(Yb + o + lo);
            acc.x += v.x; acc.y += v.y; acc.z += v.z; acc.w += v.w;
        }
        if (k < cnt) {  // odd leftover edge: only half 0 contributes (mask-FMA)
            int o = __shfl(myoff, k, 64);
            float4 v = *reinterpret_cast<const float4*>(Yb + o + lo);
            float sel = (half == 0) ? 1.0f : 0.0f;
            acc.x += v.x * sel; acc.y += v.y * sel;
            acc.z += v.z * sel; acc.w += v.w * sel;
        }
    }

    // combine halves (lane l and l+32 hold the same 4 columns)
    acc.x += __shfl_xor(acc.x, 32, 64);
    acc.y += __shfl_xor(acc.y, 32, 64);
    acc.z += __shfl_xor(acc.z, 32, 64);
    acc.w += __shfl_xor(acc.w, 32, 64);

    acc.x += selfv.x; acc.y += selfv.y; acc.z += selfv.z; acc.w += selfv.w;

    float di = dinv[node];
    float4 b = *reinterpret_cast<const float4*>(bias + l32 * 4);
    float4 h;
    h.x = fmaxf(acc.x * di + b.x, 0.f);
    h.y = fmaxf(acc.y * di + b.y, 0.f);
    h.z = fmaxf(acc.z * di + b.z, 0.f);
    h.w = fmaxf(acc.w * di + b.w, 0.f);

    if (!FUSE) {
        if (half == 0)
            *reinterpret_cast<float4*>(out + (size_t)node * FDIM + l32 * 4) = h;
    } else {
        // per-lane partial logits over this lane's 4 h components (cols 4*l32..+3)
        float lg[NCLS];
        #pragma unroll
        for (int c = 0; c < NCLS; ++c) {
            float4 w4 = *reinterpret_cast<const float4*>(&s_wl[c * FDIM + l32 * 4]);
            lg[c] = h.x * w4.x + h.y * w4.y + h.z * w4.z + h.w * w4.w;
        }
        // butterfly within each 32-lane half (both halves identical afterwards)
        #pragma unroll
        for (int off = 1; off < 32; off <<= 1) {
            #pragma unroll
            for (int c = 0; c < NCLS; ++c) lg[c] += __shfl_xor(lg[c], off, 64);
        }
        #pragma unroll
        for (int c = 0; c < NCLS; ++c) lg[c] += s_bl[c];
        float m = lg[0];
        #pragma unroll
        for (int c = 1; c < NCLS; ++c) m = fmaxf(m, lg[c]);
        float ev[NCLS];
        float sum = 0.f;
        #pragma unroll
        for (int c = 0; c < NCLS; ++c) { ev[c] = __expf(lg[c] - m); sum += ev[c]; }
        float inv = 1.0f / sum;
        float mye = 0.f;
        #pragma unroll
        for (int c = 0; c < NCLS; ++c) if (lane == c) mye = ev[c];  // static idx
        if (lane < NCLS) out[(size_t)node * NCLS + lane] = mye * inv;
    }
}

extern "C" void kernel_launch(void* const* d_in, const int* in_sizes, int n_in,
                              void* d_out, int out_size, void* d_ws, size_t ws_size,
                              hipStream_t stream) {
    const float* x  = (const float*)d_in[0];
    const int*   ei = (const int*)d_in[1];
    const float* W1 = (const float*)d_in[2];
    const float* b1 = (const float*)d_in[3];
    const float* W2 = (const float*)d_in[4];
    const float* b2 = (const float*)d_in[5];
    const float* Wl = (const float*)d_in[6];
    const float* bl = (const float*)d_in[7];
    float* out = (float*)d_out;

    int n = in_sizes[0] / FDIM;
    int e = in_sizes[1] / 2;
    const int* src = ei;
    const int* dst = ei + e;

    int nb = (n + SCAN_CHUNK - 1) / SCAN_CHUNK;  // <=1024

    // workspace layout
    float* dinv    = (float*)d_ws;                     // n
    int*   cnt     = (int*)(dinv + n);                 // n
    int*   row_ptr = cnt + n;                          // n+1
    int*   cursor  = row_ptr + n + 1;                  // n
    int*   blockSum= cursor + n;                       // nb (<=1024)
    int*   total   = blockSum + 1024;                  // 1
    int*   csr_off = total + 1;                        // e
    uintptr_t p = (uintptr_t)(csr_off + e);
    p = (p + 15) & ~(uintptr_t)15;
    float* bufA = (float*)p;                           // n*128
    float* bufB = bufA + (size_t)n * FDIM;             // n*128

    int bn = (n + 255) / 256;
    int be = (e + 255) / 256;

    // CSR + norms
    k_zero_cnt<<<bn, 256, 0, stream>>>(cnt, n);
    k_count<<<be, 256, 0, stream>>>(dst, cnt, e);
    k_scan1<<<nb, SCAN_T, 0, stream>>>(cnt, row_ptr, blockSum, dinv, n);
    k_scan2<<<1, 1024, 0, stream>>>(blockSum, total, nb);
    k_scan3<<<bn, 256, 0, stream>>>(row_ptr, cursor, blockSum, total, n);
    k_scatter<<<be, 256, 0, stream>>>(src, dst, cursor, csr_off, e);

    int bg = (n + GR - 1) / GR;
    int ba = (n + 3) / 4;

    // layer 1
    k_gemm128<<<bg, GT, 0, stream>>>(x, W1, dinv, bufA, n);
    k_agg<false><<<ba, 256, 0, stream>>>(bufA, csr_off, row_ptr, dinv, b1, Wl, bl, bufB, n);

    // layer 2 (+ fused classifier/softmax)
    k_gemm128<<<bg, GT, 0, stream>>>(bufB, W2, dinv, bufA, n);
    k_agg<true><<<ba, 256, 0, stream>>>(bufA, csr_off, row_ptr, dinv, b2, Wl, bl, out, n);
}

// Round 8
// 559.232 us; speedup vs baseline: 1.1506x; 1.1506x over previous
//
#include <hip/hip_runtime.h>
#include <hip/hip_fp16.h>

#define FDIM 128
#define NCLS 16

#define SCAN_T 256
#define SCAN_I 8
#define SCAN_CHUNK (SCAN_T * SCAN_I)  // 2048 elements per block

// ---------------- CSR build ----------------
__global__ void k_zero_cnt(int* cnt, int n) {
    int i = blockIdx.x * blockDim.x + threadIdx.x;
    if (i < n) cnt[i] = 0;
}

__global__ void k_count(const int* __restrict__ dst, int* cnt, int e) {
    int i = blockIdx.x * blockDim.x + threadIdx.x;
    if (i < e) atomicAdd(&cnt[dst[i]], 1);
}

// phase 1: block-local exclusive scan, per-block total; also computes dinv
__global__ __launch_bounds__(SCAN_T) void k_scan1(const int* __restrict__ cnt,
                                                  int* __restrict__ excl,
                                                  int* __restrict__ blockSum,
                                                  float* __restrict__ dinv, int n) {
    __shared__ int ts[SCAN_T];
    int b = blockIdx.x, t = threadIdx.x;
    int base = b * SCAN_CHUNK + t * SCAN_I;
    int v[SCAN_I];
    int s = 0;
    #pragma unroll
    for (int i = 0; i < SCAN_I; ++i) {
        int idx = base + i;
        v[i] = (idx < n) ? cnt[idx] : 0;
        if (idx < n) dinv[idx] = rsqrtf((float)(v[i] + 1));  // +1 self-loop
        s += v[i];
    }
    ts[t] = s;
    __syncthreads();
    for (int off = 1; off < SCAN_T; off <<= 1) {
        int x = (t >= off) ? ts[t - off] : 0;
        __syncthreads();
        ts[t] += x;
        __syncthreads();
    }
    int ex = (t == 0) ? 0 : ts[t - 1];
    #pragma unroll
    for (int i = 0; i < SCAN_I; ++i) {
        int idx = base + i;
        if (idx < n) excl[idx] = ex;
        ex += v[i];
    }
    if (t == SCAN_T - 1) blockSum[b] = ts[SCAN_T - 1];
}

// phase 2: single block exclusive-scans the block totals (nb <= 1024)
__global__ __launch_bounds__(1024) void k_scan2(int* blockSum, int* total, int nb) {
    __shared__ int ts[1024];
    int t = threadIdx.x;
    int v = (t < nb) ? blockSum[t] : 0;
    ts[t] = v;
    __syncthreads();
    for (int off = 1; off < 1024; off <<= 1) {
        int x = (t >= off) ? ts[t - off] : 0;
        __syncthreads();
        ts[t] += x;
        __syncthreads();
    }
    if (t < nb) blockSum[t] = (t == 0) ? 0 : ts[t - 1];
    if (t == 1023) *total = ts[1023];
}

// phase 3: add block offsets, copy to cursor, write row_ptr[n]
__global__ void k_scan3(int* __restrict__ row_ptr, int* __restrict__ cursor,
                        const int* __restrict__ blockSum, const int* __restrict__ total,
                        int n) {
    int i = blockIdx.x * blockDim.x + threadIdx.x;
    if (i < n) {
        int v = row_ptr[i] + blockSum[i / SCAN_CHUNK];
        row_ptr[i] = v;
        cursor[i] = v;
    }
    if (i == 0) row_ptr[n] = *total;
}

__global__ void k_scatter(const int* __restrict__ src, const int* __restrict__ dst,
                          int* cursor, int* __restrict__ csr_src, int e) {
    int i = blockIdx.x * blockDim.x + threadIdx.x;
    if (i >= e) return;
    int pos = atomicAdd(&cursor[dst[i]], 1);
    csr_src[pos] = src[i];
}

// ------- GEMM: Y[n,128](fp16) = (A[n,128] @ W[128,128]) * dinv[row] -------
// 512 threads, 128x128 tile, 8 rows x 4 cols per thread; A fp32 or fp16
#define GT 512
#define GR 128
template <typename T>
__global__ __launch_bounds__(GT) void k_gemm128(const T* __restrict__ A,
                                                const float* __restrict__ W,
                                                const float* __restrict__ dinv,
                                                __half* __restrict__ C, int n) {
    __shared__ float ws[128 * 128];   // [k][c], 64 KB
    __shared__ float xs[GR * 132];    // [r][k] padded to 132
    int t = threadIdx.x;
    const float4* W4 = reinterpret_cast<const float4*>(W);
    #pragma unroll
    for (int i = t; i < 128 * 32; i += GT)
        reinterpret_cast<float4*>(ws)[i] = W4[i];

    int row0 = blockIdx.x * GR;
    if constexpr (sizeof(T) == 4) {
        for (int i = t; i < GR * 32; i += GT) {
            int r = i >> 5, k4 = i & 31;
            float4 v = (row0 + r < n)
                ? reinterpret_cast<const float4*>(A)[(size_t)(row0 + r) * 32 + k4]
                : make_float4(0.f, 0.f, 0.f, 0.f);
            *reinterpret_cast<float4*>(&xs[r * 132 + k4 * 4]) = v;
        }
    } else {
        // fp16 input: 8 halves (16B) per iteration
        for (int i = t; i < GR * 16; i += GT) {
            int r = i >> 4, c8 = i & 15;
            uint4 u = make_uint4(0, 0, 0, 0);
            if (row0 + r < n)
                u = reinterpret_cast<const uint4*>(A)[(size_t)(row0 + r) * 16 + c8];
            const __half2* hp = reinterpret_cast<const __half2*>(&u);
            float2 f0 = __half22float2(hp[0]);
            float2 f1 = __half22float2(hp[1]);
            float2 f2 = __half22float2(hp[2]);
            float2 f3 = __half22float2(hp[3]);
            float* d = &xs[r * 132 + c8 * 8];
            *reinterpret_cast<float4*>(d)     = make_float4(f0.x, f0.y, f1.x, f1.y);
            *reinterpret_cast<float4*>(d + 4) = make_float4(f2.x, f2.y, f3.x, f3.y);
        }
    }
    __syncthreads();

    int tc = t & 31, tr = t >> 5;   // tr 0..15
    int c0 = tc * 4, r0 = tr * 8;
    float4 acc[8] = {};
    for (int k = 0; k < 128; k += 4) {
        float4 a[8];
        #pragma unroll
        for (int i = 0; i < 8; ++i)
            a[i] = *reinterpret_cast<const float4*>(&xs[(r0 + i) * 132 + k]);
        #pragma unroll
        for (int kk = 0; kk < 4; ++kk) {
            float4 w4 = *reinterpret_cast<const float4*>(&ws[(k + kk) * 128 + c0]);
            #pragma unroll
            for (int i = 0; i < 8; ++i) {
                float av = (kk == 0) ? a[i].x : (kk == 1) ? a[i].y : (kk == 2) ? a[i].z : a[i].w;
                acc[i].x += av * w4.x;
                acc[i].y += av * w4.y;
                acc[i].z += av * w4.z;
                acc[i].w += av * w4.w;
            }
        }
    }
    #pragma unroll
    for (int i = 0; i < 8; ++i) {
        int r = row0 + r0 + i;
        if (r < n) {
            float s = dinv[r];
            __half2 h0 = __float22half2_rn(make_float2(acc[i].x * s, acc[i].y * s));
            __half2 h1 = __float22half2_rn(make_float2(acc[i].z * s, acc[i].w * s));
            uint2 pack;
            pack.x = *reinterpret_cast<unsigned int*>(&h0);
            pack.y = *reinterpret_cast<unsigned int*>(&h1);
            reinterpret_cast<uint2*>(C)[(size_t)r * 32 + tc] = pack;  // 8B at col c0
        }
    }
}

// ---------------- aggregation (+ optional fused classifier/softmax) ----------------
// one wave per node; 64 lanes x half2 cover the 128-dim fp16 row; whole wave per
// edge; coalesced index load + shfl broadcast. 8-edge groups accumulate via a
// v_pk_add_f16 tree (7 packed adds), ONE cvt to f32 per group per lane.
template <bool FUSE>
__global__ __launch_bounds__(256) void k_agg(const __half* __restrict__ Y,
                                             const int* __restrict__ csr_src,
                                             const int* __restrict__ row_ptr,
                                             const float* __restrict__ dinv,
                                             const float* __restrict__ bias,
                                             const float* __restrict__ Wl,
                                             const float* __restrict__ bl,
                                             __half* __restrict__ hout,
                                             float* __restrict__ out, int n) {
    __shared__ float s_wl[NCLS * FDIM];  // transposed: [c][k]
    __shared__ float s_bl[NCLS];
    if (FUSE) {
        for (int i = threadIdx.x; i < FDIM * NCLS / 4; i += 256) {
            int k = i >> 2, c4 = (i & 3) * 4;
            float4 v = reinterpret_cast<const float4*>(Wl)[i];
            s_wl[(c4 + 0) * FDIM + k] = v.x;
            s_wl[(c4 + 1) * FDIM + k] = v.y;
            s_wl[(c4 + 2) * FDIM + k] = v.z;
            s_wl[(c4 + 3) * FDIM + k] = v.w;
        }
        if (threadIdx.x < NCLS) s_bl[threadIdx.x] = bl[threadIdx.x];
        __syncthreads();
    }

    int node = blockIdx.x * 4 + (threadIdx.x >> 6);
    if (node >= n) return;
    int lane = threadIdx.x & 63;

    const __half2* Y2 = reinterpret_cast<const __half2*>(Y);
    float2 acc = __half22float2(Y2[(size_t)node * 64 + lane]);  // self term
    int beg = row_ptr[node], end = row_ptr[node + 1];

    for (int j0 = beg; j0 < end; j0 += 64) {
        int cnt = min(64, end - j0);
        int myidx = (j0 + lane < end) ? csr_src[j0 + lane] : 0;
        int k = 0;
        for (; k + 8 <= cnt; k += 8) {
            int s0 = __shfl(myidx, k + 0, 64), s1 = __shfl(myidx, k + 1, 64);
            int s2 = __shfl(myidx, k + 2, 64), s3 = __shfl(myidx, k + 3, 64);
            int s4 = __shfl(myidx, k + 4, 64), s5 = __shfl(myidx, k + 5, 64);
            int s6 = __shfl(myidx, k + 6, 64), s7 = __shfl(myidx, k + 7, 64);
            __half2 v0 = Y2[(size_t)s0 * 64 + lane];
            __half2 v1 = Y2[(size_t)s1 * 64 + lane];
            __half2 v2 = Y2[(size_t)s2 * 64 + lane];
            __half2 v3 = Y2[(size_t)s3 * 64 + lane];
            __half2 v4 = Y2[(size_t)s4 * 64 + lane];
            __half2 v5 = Y2[(size_t)s5 * 64 + lane];
            __half2 v6 = Y2[(size_t)s6 * 64 + lane];
            __half2 v7 = Y2[(size_t)s7 * 64 + lane];
            // packed-fp16 tree (depth 3), single cvt to fp32
            __half2 p0 = __hadd2(v0, v1);
            __half2 p1 = __hadd2(v2, v3);
            __half2 p2 = __hadd2(v4, v5);
            __half2 p3 = __hadd2(v6, v7);
            __half2 q0 = __hadd2(p0, p1);
            __half2 q1 = __hadd2(p2, p3);
            __half2 r  = __hadd2(q0, q1);
            float2 f = __half22float2(r);
            acc.x += f.x;
            acc.y += f.y;
        }
        for (; k < cnt; ++k) {
            int s = __shfl(myidx, k, 64);
            float2 f = __half22float2(Y2[(size_t)s * 64 + lane]);
            acc.x += f.x;
            acc.y += f.y;
        }
    }

    float di = dinv[node];
    float2 b = reinterpret_cast<const float2*>(bias)[lane];
    float hx = fmaxf(acc.x * di + b.x, 0.f);
    float hy = fmaxf(acc.y * di + b.y, 0.f);

    if (!FUSE) {
        reinterpret_cast<__half2*>(hout)[(size_t)node * 64 + lane] =
            __float22half2_rn(make_float2(hx, hy));
    } else {
        float lg[NCLS];
        #pragma unroll
        for (int c = 0; c < NCLS; ++c) {
            float2 w2 = *reinterpret_cast<const float2*>(&s_wl[c * FDIM + lane * 2]);
            lg[c] = hx * w2.x + hy * w2.y;
        }
        #pragma unroll
        for (int off = 1; off < 64; off <<= 1) {
            #pragma unroll
            for (int c = 0; c < NCLS; ++c) lg[c] += __shfl_xor(lg[c], off, 64);
        }
        #pragma unroll
        for (int c = 0; c < NCLS; ++c) lg[c] += s_bl[c];
        float m = lg[0];
        #pragma unroll
        for (int c = 1; c < NCLS; ++c) m = fmaxf(m, lg[c]);
        float ev[NCLS];
        float sum = 0.f;
        #pragma unroll
        for (int c = 0; c < NCLS; ++c) { ev[c] = __expf(lg[c] - m); sum += ev[c]; }
        float inv = 1.0f / sum;
        float mye = 0.f;
        #pragma unroll
        for (int c = 0; c < NCLS; ++c) if (lane == c) mye = ev[c];  // static idx
        if (lane < NCLS) out[(size_t)node * NCLS + lane] = mye * inv;
    }
}

extern "C" void kernel_launch(void* const* d_in, const int* in_sizes, int n_in,
                              void* d_out, int out_size, void* d_ws, size_t ws_size,
                              hipStream_t stream) {
    const float* x  = (const float*)d_in[0];
    const int*   ei = (const int*)d_in[1];
    const float* W1 = (const float*)d_in[2];
    const float* b1 = (const float*)d_in[3];
    const float* W2 = (const float*)d_in[4];
    const float* b2 = (const float*)d_in[5];
    const float* Wl = (const float*)d_in[6];
    const float* bl = (const float*)d_in[7];
    float* out = (float*)d_out;

    int n = in_sizes[0] / FDIM;
    int e = in_sizes[1] / 2;
    const int* src = ei;
    const int* dst = ei + e;

    int nb = (n + SCAN_CHUNK - 1) / SCAN_CHUNK;  // <=1024

    // workspace layout
    float* dinv    = (float*)d_ws;                     // n
    int*   cnt     = (int*)(dinv + n);                 // n
    int*   row_ptr = cnt + n;                          // n+1
    int*   cursor  = row_ptr + n + 1;                  // n
    int*   blockSum= cursor + n;                       // nb (<=1024)
    int*   total   = blockSum + 1024;                  // 1
    int*   csr_src = total + 1;                        // e
    uintptr_t p = (uintptr_t)(csr_src + e);
    p = (p + 15) & ~(uintptr_t)15;
    __half* bufA = (__half*)p;                         // n*128 halves
    __half* bufB = bufA + (size_t)n * FDIM;            // n*128 halves

    int bn = (n + 255) / 256;
    int be = (e + 255) / 256;

    // CSR + norms
    k_zero_cnt<<<bn, 256, 0, stream>>>(cnt, n);
    k_count<<<be, 256, 0, stream>>>(dst, cnt, e);
    k_scan1<<<nb, SCAN_T, 0, stream>>>(cnt, row_ptr, blockSum, dinv, n);
    k_scan2<<<1, 1024, 0, stream>>>(blockSum, total, nb);
    k_scan3<<<bn, 256, 0, stream>>>(row_ptr, cursor, blockSum, total, n);
    k_scatter<<<be, 256, 0, stream>>>(src, dst, cursor, csr_src, e);

    int bg = (n + GR - 1) / GR;
    int ba = (n + 3) / 4;

    // layer 1
    k_gemm128<float><<<bg, GT, 0, stream>>>(x, W1, dinv, bufA, n);
    k_agg<false><<<ba, 256, 0, stream>>>(bufA, csr_src, row_ptr, dinv, b1, Wl, bl, bufB, out, n);

    // layer 2 (+ fused classifier/softmax)
    k_gemm128<__half><<<bg, GT, 0, stream>>>(bufB, W2, dinv, bufA, n);
    k_agg<true><<<ba, 256, 0, stream>>>(bufA, csr_src, row_ptr, dinv, b2, Wl, bl, bufB, out, n);
}